// Round 12
// baseline (490.065 us; speedup 1.0000x reference)
//
#include <hip/hip_runtime.h>
#include <math.h>

#define TPB 256
#define BNODES 256     // nodes per bucket (col>>8)
#define EPB 8192       // edges per block in hist/bscatter
#define SENT (-1)
#define MAXBKT 512     // padded bucket-array size (NBKT=395 for this problem)
#define STAGE_CAP 14144  // >= EPB + 15*NBKT(395) = 14117

typedef _Float16 h8 __attribute__((ext_vector_type(8)));
typedef _Float16 hf;

// ===================== threefry2x32-20 (JAX-exact, PARTITIONABLE mode) + gumbel =====================
__device__ __forceinline__ float jax_gumbel(unsigned key, unsigned i) {
  unsigned x0 = 0u, x1 = i;
  unsigned ks0 = 0u, ks1 = key, ks2 = key ^ 0x1BD11BDAu;
  x0 += ks0; x1 += ks1;
#define TFR(r) { x0 += x1; x1 = (x1 << (r)) | (x1 >> (32 - (r))); x1 ^= x0; }
  TFR(13) TFR(15) TFR(26) TFR(6)
  x0 += ks1; x1 += ks2 + 1u;
  TFR(17) TFR(29) TFR(16) TFR(24)
  x0 += ks2; x1 += ks0 + 2u;
  TFR(13) TFR(15) TFR(26) TFR(6)
  x0 += ks0; x1 += ks1 + 3u;
  TFR(17) TFR(29) TFR(16) TFR(24)
  x0 += ks1; x1 += ks2 + 4u;
  TFR(13) TFR(15) TFR(26) TFR(6)
  x0 += ks2; x1 += ks0 + 5u;
#undef TFR
  unsigned bits = x0 ^ x1;
  float f = __uint_as_float((bits >> 9) | 0x3f800000u) - 1.0f;
  float u = (f == 0.0f) ? 1.17549435e-38f : f;
  return -logf(-logf(u));
}

// ===================== pass 1a: coarse bucket histogram (LDS atomics only) =====================
__global__ void hist_k(const int* __restrict__ col, int* __restrict__ hist,
                       int ne, int nbkt, int nblk) {
  __shared__ int h[1024];
  int t = threadIdx.x;
  for (int i = t; i < nbkt; i += TPB) h[i] = 0;
  __syncthreads();
  int base = blockIdx.x * EPB;
#pragma unroll
  for (int k = 0; k < EPB / TPB; k++) {
    int idx = base + k * TPB + t;
    if (idx < ne) atomicAdd(&h[col[idx] >> 8], 1);
  }
  __syncthreads();
  for (int i = t; i < nbkt; i += TPB) hist[(size_t)i * nblk + blockIdx.x] = h[i];
}

// ===================== real per-bucket totals =====================
__global__ void breal_k(const int* __restrict__ hist, int* __restrict__ breal, int nblk) {
  int bkt = blockIdx.x;
  int t = threadIdx.x;
  int s = 0;
  for (int b = t; b < nblk; b += TPB) s += hist[(size_t)bkt * nblk + b];
  __shared__ int red[TPB];
  red[t] = s; __syncthreads();
  for (int st = 128; st > 0; st >>= 1) { if (t < st) red[t] += red[t + st]; __syncthreads(); }
  if (t == 0) breal[bkt] = red[0];
}

// ===================== scans (PAD=1: pad each value to multiple of 16) =====================
template <int PAD>
__global__ void scan1_k(const int* __restrict__ a, int* __restrict__ bsums, int n) {
  int t = threadIdx.x;
  int base = blockIdx.x * 1024 + t * 4;
  int s = 0;
#pragma unroll
  for (int k = 0; k < 4; k++) {
    int i = base + k;
    if (i < n) { int v = a[i]; if (PAD) v = (v + 15) & ~15; s += v; }
  }
  __shared__ int red[TPB];
  red[t] = s; __syncthreads();
  for (int st = 128; st > 0; st >>= 1) { if (t < st) red[t] += red[t + st]; __syncthreads(); }
  if (t == 0) bsums[blockIdx.x] = red[0];
}

__global__ void scan_single_k(int* a, int m) {
  __shared__ int sc[TPB];
  int t = threadIdx.x;
  int v[4]; int s = 0;
#pragma unroll
  for (int k = 0; k < 4; k++) { int i = t * 4 + k; v[k] = (i < m) ? a[i] : 0; s += v[k]; }
  sc[t] = s; __syncthreads();
  for (int off = 1; off < TPB; off <<= 1) {
    int add = (t >= off) ? sc[t - off] : 0;
    __syncthreads();
    sc[t] += add;
    __syncthreads();
  }
  int excl = sc[t] - s;
#pragma unroll
  for (int k = 0; k < 4; k++) { int i = t * 4 + k; if (i < m) a[i] = excl; excl += v[k]; }
  if (t == TPB - 1) a[m] = excl;
}

template <int PAD>
__global__ void scan3_k(const int* __restrict__ a, const int* __restrict__ bsums,
                        int* __restrict__ outp, int n, int nb) {
  int t = threadIdx.x;
  int base = blockIdx.x * 1024 + t * 4;
  int v[4]; int tsum = 0;
#pragma unroll
  for (int k = 0; k < 4; k++) {
    int vv = 0;
    if (base + k < n) { vv = a[base + k]; if (PAD) vv = (vv + 15) & ~15; }
    v[k] = vv; tsum += vv;
  }
  __shared__ int sc[TPB];
  sc[t] = tsum; __syncthreads();
  for (int off = 1; off < TPB; off <<= 1) {
    int add = (t >= off) ? sc[t - off] : 0;
    __syncthreads();
    sc[t] += add;
    __syncthreads();
  }
  int excl = sc[t] - tsum + bsums[blockIdx.x];
#pragma unroll
  for (int k = 0; k < 4; k++) { if (base + k < n) outp[base + k] = excl; excl += v[k]; }
  if (blockIdx.x == 0 && t == 0) outp[n] = bsums[nb];
}

// ===================== pass 1b: LDS-staged bucket scatter + fused edge->float copy ==========
__global__ void __launch_bounds__(TPB, 1)
bscatter_k(const int* __restrict__ row, const int* __restrict__ col,
           const int* __restrict__ histP, int* __restrict__ pairs,
           float* __restrict__ e0, float* __restrict__ e1,
           int ne, int nbkt, int nblk) {
  __shared__ int sbase[MAXBKT], lofs[MAXBKT], lcur[MAXBKT], lsz[MAXBKT];
  __shared__ int ssc[TPB];
  __shared__ int stage[STAGE_CAP];
  int t = threadIdx.x;
  int b = blockIdx.x;
  int i0 = 2 * t, i1 = 2 * t + 1;
  int g0 = 0, L0 = 0, g1 = 0, L1 = 0;
  if (i0 < nbkt) { size_t f = (size_t)i0 * nblk + b; g0 = histP[f]; L0 = histP[f + 1] - g0; }
  if (i1 < nbkt) { size_t f = (size_t)i1 * nblk + b; g1 = histP[f]; L1 = histP[f + 1] - g1; }
  int s = L0 + L1;
  ssc[t] = s; __syncthreads();
  for (int off = 1; off < TPB; off <<= 1) {
    int add = (t >= off) ? ssc[t - off] : 0;
    __syncthreads();
    ssc[t] += add;
    __syncthreads();
  }
  int excl = ssc[t] - s;
  if (i0 < nbkt) { sbase[i0] = g0; lofs[i0] = excl; lcur[i0] = excl; lsz[i0] = L0; }
  if (i1 < nbkt) { sbase[i1] = g1; lofs[i1] = excl + L0; lcur[i1] = excl + L0; lsz[i1] = L1; }
  __syncthreads();
  int base0 = b * EPB;
#pragma unroll
  for (int k = 0; k < EPB / TPB; k++) {
    int idx = base0 + k * TPB + t;
    if (idx < ne) {
      int c = col[idx];
      int r = row[idx];
      int p = atomicAdd(&lcur[c >> 8], 1);
      stage[p] = (r << 8) | (c & 255);
      e0[idx] = (float)r;       // fused edgecopy (coalesced dword stores)
      e1[idx] = (float)c;
    }
  }
  __syncthreads();
  for (int i = t; i < nbkt; i += TPB) {
    int en = lcur[i], pe = lofs[i] + lsz[i];
    for (int p = en; p < pe; p++) stage[p] = SENT;
  }
  __syncthreads();
  int4* gp = (int4*)pairs;
  const int4* sp = (const int4*)stage;
  for (int i = t; i < nbkt; i += TPB) {
    int gb = sbase[i] >> 2, lb = lofs[i] >> 2, m = lsz[i] >> 2;
    for (int q = 0; q < m; q++) gp[gb + q] = sp[lb + q];
  }
}

// ===================== pass 2: per-bucket CSR build =====================
__global__ void bbuild_k(const int* __restrict__ pairs, const int* __restrict__ histP,
                         const int* __restrict__ bbase, int nblk, int* __restrict__ rp,
                         float* __restrict__ dinv, int* __restrict__ csr, int n, int ne) {
  int bkt = blockIdx.x;
  int lo = bkt << 8;
  int t = threadIdx.x;
  int pstart = histP[(size_t)bkt * nblk];
  int pend   = histP[(size_t)(bkt + 1) * nblk];
  int rbase  = bbase[bkt];
  __shared__ int cnt[BNODES], sc[BNODES], pos[BNODES];
  cnt[t] = 0; __syncthreads();
  for (int p = pstart + t; p < pend; p += TPB) {
    int e = pairs[p];
    if (e >= 0) atomicAdd(&cnt[e & 255], 1);
  }
  __syncthreads();
  int own = cnt[t];
  sc[t] = own; __syncthreads();
  for (int off = 1; off < BNODES; off <<= 1) {
    int add = (t >= off) ? sc[t - off] : 0;
    __syncthreads();
    sc[t] += add;
    __syncthreads();
  }
  int excl = sc[t] - own;
  if (lo + t < n) {
    rp[lo + t] = rbase + excl;
    dinv[lo + t] = 1.0f / sqrtf((float)(own + 1));
  }
  pos[t] = rbase + excl;
  __syncthreads();
  for (int p = pstart + t; p < pend; p += TPB) {
    int e = pairs[p];
    if (e >= 0) {
      int q = atomicAdd(&pos[e & 255], 1);
      csr[q] = e >> 8;
    }
  }
  if (bkt == 0 && t == 0) rp[n] = ne;
}

// ===================== prep: W23 = W2@W3 (16x32), bvA = b1@W23, bvB = b2@W3 =====================
__global__ void prep_k(const float* __restrict__ W2, const float* __restrict__ W3,
                       const float* __restrict__ b1, const float* __restrict__ b2,
                       float* __restrict__ W23, float* __restrict__ bvA, float* __restrict__ bvB) {
  int t = threadIdx.x;
  for (int idx = t; idx < 512; idx += TPB) {
    int i = idx >> 5, j = idx & 31;
    float s = 0.f;
    for (int k = 0; k < 24; k++) s += W2[i * 24 + k] * W3[k * 32 + j];
    W23[idx] = s;
  }
  __syncthreads();
  if (t < 32) {
    float sA = 0.f;
    for (int i = 0; i < 16; i++) sA += b1[i] * W23[i * 32 + t];
    bvA[t] = sA;
    float sB = 0.f;
    for (int k = 0; k < 24; k++) sB += b2[k] * W3[k * 32 + t];
    bvB[t] = sB;
  }
}

// ===================== s0 = dinv * (x W1), fp16 output (16-wide) =====================
__global__ void gemm16h_k(const float* __restrict__ A, const float* __restrict__ A2, int nsplit,
                          const float* __restrict__ W, const float* __restrict__ dinv,
                          hf* __restrict__ out, int n) {
  constexpr int FIN = 32, FOUT = 16, FP = 16;
  constexpr int NODES = TPB / FP;
  __shared__ float Ws[FIN * FOUT];
  __shared__ float Hs[NODES * (FIN + 1)];
  int t = threadIdx.x;
  int base = blockIdx.x * NODES;
  for (int i = t; i < FIN * FOUT; i += TPB) Ws[i] = W[i];
  for (int i = t; i < NODES * FIN; i += TPB) {
    int nl = i / FIN, k = i - nl * FIN;
    int g = base + nl;
    float v = 0.f;
    if (g < n) v = (g < nsplit) ? A[(size_t)g * FIN + k] : A2[(size_t)(g - nsplit) * FIN + k];
    Hs[nl * (FIN + 1) + k] = v;
  }
  __syncthreads();
  int nl = t / FP, j = t % FP;
  int g = base + nl;
  if (g < n) {
    float acc = 0.f;
#pragma unroll
    for (int k = 0; k < FIN; k++) acc += Hs[nl * (FIN + 1) + k] * Ws[k * FOUT + j];
    out[(size_t)g * FOUT + j] = (hf)(acc * dinv[g]);
  }
}

// ===================== fp16 hop + fused scalar chain: 8 nodes/wave =====================
__global__ void agghs_k(const h8* __restrict__ ts, const int* __restrict__ csr,
                        const int* __restrict__ rp, const float* __restrict__ dinv,
                        const float* __restrict__ sin, float* __restrict__ u_out,
                        float* __restrict__ us_out, h8* __restrict__ outv, int n) {
  int wave = blockIdx.x * (TPB / 64) + (threadIdx.x >> 6);
  int lane = threadIdx.x & 63;
  int j = lane & 1;
  int grp = (lane >> 1) & 3;
  int nl = lane >> 3;
  int c = wave * 8 + nl;
  bool valid = (c < n);
  float acc[8] = {0.f, 0.f, 0.f, 0.f, 0.f, 0.f, 0.f, 0.f};
  float accS = 0.f;
  if (valid) {
    int s = rp[c], e = rp[c + 1];
    for (int p = s + grp; p < e; p += 4) {
      int r = csr[p];
      h8 v = ts[r * 2 + j];
#pragma unroll
      for (int k = 0; k < 8; k++) acc[k] += (float)v[k];
      if (j == 0) accS += sin[r];
    }
  }
#pragma unroll
  for (int off = 2; off <= 4; off <<= 1) {
#pragma unroll
    for (int k = 0; k < 8; k++) acc[k] += __shfl_xor(acc[k], off, 64);
    accS += __shfl_xor(accS, off, 64);
  }
  if (valid && grp == 0) {
    h8 self = ts[c * 2 + j];
    float d = dinv[c];
    float scl = d * d;
    h8 o;
#pragma unroll
    for (int k = 0; k < 8; k++) o[k] = (hf)(scl * (acc[k] + (float)self[k]));
    outv[c * 2 + j] = o;
    if (j == 0) {
      float u = d * (accS + sin[c]);
      u_out[c] = u;
      if (us_out) us_out[c] = u * d;
    }
  }
}

// ===================== final hop + fused combine (8 nodes/wave, 32 nodes/block) =====================
__global__ void agghc_k(const h8* __restrict__ ts, const int* __restrict__ csr,
                        const int* __restrict__ rp, const float* __restrict__ dinv,
                        const float* __restrict__ a1, const float* __restrict__ a2,
                        const float* __restrict__ W23, const float* __restrict__ bvA,
                        const float* __restrict__ bvB, const float* __restrict__ b3,
                        float* __restrict__ out, int n) {
  __shared__ float Ws[512], vA[32], vB[32], vb[32];
  __shared__ float t3s[32][17];
  int t = threadIdx.x;
  for (int i = t; i < 512; i += TPB) Ws[i] = W23[i];
  if (t < 32) { vA[t] = bvA[t]; vB[t] = bvB[t]; vb[t] = b3[t]; }
  int wave = t >> 6;
  int lane = t & 63;
  int j = lane & 1;
  int grp = (lane >> 1) & 3;
  int nl = lane >> 3;
  int nlb = wave * 8 + nl;              // node-in-block 0..31
  int c = blockIdx.x * 32 + nlb;
  bool valid = (c < n);
  float acc[8] = {0.f, 0.f, 0.f, 0.f, 0.f, 0.f, 0.f, 0.f};
  if (valid) {
    int s = rp[c], e = rp[c + 1];
    for (int p = s + grp; p < e; p += 4) {
      int r = csr[p];
      h8 v = ts[r * 2 + j];
#pragma unroll
      for (int k = 0; k < 8; k++) acc[k] += (float)v[k];
    }
  }
#pragma unroll
  for (int off = 2; off <= 4; off <<= 1) {
#pragma unroll
    for (int k = 0; k < 8; k++) acc[k] += __shfl_xor(acc[k], off, 64);
  }
  if (valid && grp == 0) {
    h8 self = ts[c * 2 + j];
    float d = dinv[c];
#pragma unroll
    for (int k = 0; k < 8; k++) t3s[nlb][j * 8 + k] = d * (acc[k] + (float)self[k]);
  }
  __syncthreads();
  int n2 = t >> 3, jb = t & 7;          // 32 nodes x 8 base channels
  int g = blockIdx.x * 32 + n2;
  if (g < n) {
    float av = a1[g], bv = a2[g];
#pragma unroll
    for (int q = 0; q < 4; q++) {
      int j2 = jb + q * 8;
      float acc2 = 0.f;
#pragma unroll
      for (int k = 0; k < 16; k++) acc2 += t3s[n2][k] * Ws[k * 32 + j2];
      out[(size_t)g * 32 + j2] = acc2 + bv * vA[j2] + av * vB[j2] + vb[j2];
    }
  }
}

// ===================== fused heads + online-softmax partials (LDS-tiled, NO register row) ==========
// pm layout (stride 512): [0..)=m1, [512..)=s1, [1024..)=m2, [1536..)=s2
__global__ void heads_k(const float* __restrict__ h3,
                        const float* __restrict__ Ws1, const float* __restrict__ bs1,
                        const float* __restrict__ ws2, const float* __restrict__ bs2,
                        const float* __restrict__ We1, const float* __restrict__ be1,
                        const float* __restrict__ we2, const float* __restrict__ be2,
                        float* __restrict__ slog, float* __restrict__ elog,
                        float* __restrict__ pm, int n) {
  __shared__ float W1s[32 * 16], W2s[32 * 24], b1s[16], b2s[24], v1s[16], v2s[24];
  __shared__ float Hs[TPB][33];
  int t = threadIdx.x;
  for (int i = t; i < 32 * 16; i += TPB) W1s[i] = Ws1[i];
  for (int i = t; i < 32 * 24; i += TPB) W2s[i] = We1[i];
  if (t < 16) { b1s[t] = bs1[t]; v1s[t] = ws2[t]; }
  if (t < 24) { b2s[t] = be1[t]; v2s[t] = we2[t]; }
  // coalesced tile load: h3[block*256 .. +256)[0..32) -> Hs[node][k]
  size_t tbase = (size_t)blockIdx.x * TPB * 32;
  for (int i = t; i < TPB * 32; i += TPB) {
    int nl = i >> 5, k = i & 31;
    size_t gi = tbase + i;
    Hs[nl][k] = (gi < (size_t)n * 32) ? h3[gi] : 0.f;
  }
  __syncthreads();
  int i = blockIdx.x * TPB + t;
  float s = -3.402823466e+38f, e2 = -3.402823466e+38f;
  if (i < n) {
    s = bs2[0];
#pragma unroll
    for (int j = 0; j < 16; j++) {
      float a = b1s[j];
#pragma unroll
      for (int k = 0; k < 32; k++) a += Hs[t][k] * W1s[k * 16 + j];
      a = fminf(fmaxf(a, 0.f), 6.f);
      s += a * v1s[j];
    }
    e2 = be2[0];
#pragma unroll
    for (int j = 0; j < 24; j++) {
      float a = b2s[j];
#pragma unroll
      for (int k = 0; k < 32; k++) a += Hs[t][k] * W2s[k * 24 + j];
      a = fminf(fmaxf(a, 0.f), 6.f);
      e2 += a * v2s[j];
    }
    slog[i] = s;
    elog[i] = e2;
  }
  __syncthreads();
  // block online-softmax partials (reuse Hs as scratch: 4 arrays of TPB floats)
  float* sm1 = &Hs[0][0];
  float* ss1 = sm1 + TPB;
  float* sm2 = ss1 + TPB;
  float* ss2 = sm2 + TPB;
  sm1[t] = s;  ss1[t] = (i < n) ? 1.f : 0.f;
  sm2[t] = e2; ss2[t] = (i < n) ? 1.f : 0.f;
  __syncthreads();
  for (int st = 128; st > 0; st >>= 1) {
    if (t < st) {
      float M = fmaxf(sm1[t], sm1[t + st]);
      ss1[t] = ss1[t] * expf(sm1[t] - M) + ss1[t + st] * expf(sm1[t + st] - M);
      sm1[t] = M;
      float M2 = fmaxf(sm2[t], sm2[t + st]);
      ss2[t] = ss2[t] * expf(sm2[t] - M2) + ss2[t + st] * expf(sm2[t + st] - M2);
      sm2[t] = M2;
    }
    __syncthreads();
  }
  if (t == 0) {
    pm[blockIdx.x] = sm1[0]; pm[512 + blockIdx.x] = ss1[0];
    pm[1024 + blockIdx.x] = sm2[0]; pm[1536 + blockIdx.x] = ss2[0];
  }
}

__global__ void osm_fin_k(const float* __restrict__ pm, float* __restrict__ fsc, int nb) {
  int t = threadIdx.x;
  float m1 = -3.402823466e+38f, s1 = 0.f, m2 = -3.402823466e+38f, s2 = 0.f;
  for (int i = t; i < nb; i += TPB) {
    float bm1 = pm[i], bs1v = pm[512 + i];
    float M = fmaxf(m1, bm1);
    s1 = s1 * expf(m1 - M) + bs1v * expf(bm1 - M); m1 = M;
    float bm2 = pm[1024 + i], bs2v = pm[1536 + i];
    float M2 = fmaxf(m2, bm2);
    s2 = s2 * expf(m2 - M2) + bs2v * expf(bm2 - M2); m2 = M2;
  }
  __shared__ float sm1[TPB], ss1[TPB], sm2[TPB], ss2[TPB];
  sm1[t] = m1; ss1[t] = s1; sm2[t] = m2; ss2[t] = s2; __syncthreads();
  for (int st = 128; st > 0; st >>= 1) {
    if (t < st) {
      float M = fmaxf(sm1[t], sm1[t + st]);
      ss1[t] = ss1[t] * expf(sm1[t] - M) + ss1[t + st] * expf(sm1[t + st] - M);
      sm1[t] = M;
      float M2 = fmaxf(sm2[t], sm2[t + st]);
      ss2[t] = ss2[t] * expf(sm2[t] - M2) + ss2[t + st] * expf(sm2[t + st] - M2);
      sm2[t] = M2;
    }
    __syncthreads();
  }
  if (t == 0) { fsc[0] = sm1[0]; fsc[2] = ss1[0]; fsc[1] = sm2[0]; fsc[3] = ss2[0]; }
}

// ===================== fused probs write + gumbel argmax =====================
template <int HEAD>
__global__ void pargmax_k(const float* __restrict__ logit, const float* __restrict__ fsc,
                          const int* __restrict__ isc, float* __restrict__ outp,
                          unsigned key, int n, int ngraph, float* pval, int* pidx) {
  int t = threadIdx.x;
  float mx = fsc[HEAD], sm = fsc[2 + HEAD];
  int ban = HEAD ? isc[0] : -1;
  float bv = -3.402823466e+38f;
  int bi = 0x7fffffff;
  for (int i = blockIdx.x * TPB + t; i < n; i += gridDim.x * TPB) {
    float p = expf(logit[i] - mx) / sm;
    if (HEAD == 0) { if (i >= ngraph) p = 0.f; }
    else           { if (i == ban) p = 0.f; }
    if (p == 0.f) p = 1e-10f;
    outp[i] = p;
    float v = logf(p) + jax_gumbel(key, (unsigned)i);
    if (v > bv) { bv = v; bi = i; }
  }
  __shared__ float sv[TPB]; __shared__ int si[TPB];
  sv[t] = bv; si[t] = bi; __syncthreads();
  for (int st = 128; st > 0; st >>= 1) {
    if (t < st) {
      float v2 = sv[t + st]; int i2 = si[t + st];
      if (v2 > sv[t] || (v2 == sv[t] && i2 < si[t])) { sv[t] = v2; si[t] = i2; }
    }
    __syncthreads();
  }
  if (t == 0) { pval[blockIdx.x] = sv[0]; pidx[blockIdx.x] = si[0]; }
}

__global__ void argmax_fin_k(const float* pval, const int* pidx, int nb,
                             int* isc, float* dnode) {
  int t = threadIdx.x;
  float bv = (t < nb) ? pval[t] : -3.402823466e+38f;
  int bi = (t < nb) ? pidx[t] : 0x7fffffff;
  __shared__ float sv[TPB]; __shared__ int si[TPB];
  sv[t] = bv; si[t] = bi; __syncthreads();
  for (int st = 128; st > 0; st >>= 1) {
    if (t < st) {
      float v2 = sv[t + st]; int i2 = si[t + st];
      if (v2 > sv[t] || (v2 == sv[t] && i2 < si[t])) { sv[t] = v2; si[t] = i2; }
    }
    __syncthreads();
  }
  if (t == 0) { isc[0] = si[0]; dnode[0] = (float)si[0]; }
}

__global__ void argmax_fin_end_k(const float* pval, const int* pidx, int nb,
                                 const int* isc, float* p_end, float* p_e0, float* p_e1) {
  int t = threadIdx.x;
  float bv = (t < nb) ? pval[t] : -3.402823466e+38f;
  int bi = (t < nb) ? pidx[t] : 0x7fffffff;
  __shared__ float sv[TPB]; __shared__ int si[TPB];
  sv[t] = bv; si[t] = bi; __syncthreads();
  for (int st = 128; st > 0; st >>= 1) {
    if (t < st) {
      float v2 = sv[t + st]; int i2 = si[t + st];
      if (v2 > sv[t] || (v2 == sv[t] && i2 < si[t])) { sv[t] = v2; si[t] = i2; }
    }
    __syncthreads();
  }
  if (t == 0) {
    int en = si[0];
    p_end[0] = (float)en;
    p_e0[0] = (float)isc[0];
    p_e1[0] = (float)en;
  }
}

// ===================== launch =====================
extern "C" void kernel_launch(void* const* d_in, const int* in_sizes, int n_in,
                              void* d_out, int out_size, void* d_ws, size_t ws_size,
                              hipStream_t stream) {
  const float* x    = (const float*)d_in[0];
  const float* cand = (const float*)d_in[1];
  const int*   ei   = (const int*)d_in[2];
  const float* W1 = (const float*)d_in[3];  const float* b1  = (const float*)d_in[4];
  const float* W2 = (const float*)d_in[5];  const float* b2  = (const float*)d_in[6];
  const float* W3 = (const float*)d_in[7];  const float* b3  = (const float*)d_in[8];
  const float* Ws1= (const float*)d_in[9];  const float* bs1 = (const float*)d_in[10];
  const float* Ws2= (const float*)d_in[11]; const float* bs2 = (const float*)d_in[12];
  const float* We1= (const float*)d_in[13]; const float* be1 = (const float*)d_in[14];
  const float* We2= (const float*)d_in[15]; const float* be2 = (const float*)d_in[16];

  const int nG = in_sizes[0] / 32, nC = in_sizes[1] / 32;
  const int n  = nG + nC;            // 101000
  const int ne = in_sizes[2] / 2;    // 3200000

  float* out = (float*)d_out;
  const size_t OFF1 = (size_t)n * 32;
  const size_t OFF2 = OFF1 + n;
  const size_t OFF3 = OFF2 + n;
  const size_t OFF4 = OFF3 + 1;
  const size_t OFF5 = OFF4 + 1;     // edge_index_new region: 2*(ne+1) floats

  const int NBKT = (n + BNODES - 1) / BNODES;
  const int NBLK = (ne + EPB - 1) / EPB;
  const int H    = NBKT * NBLK;
  const int nbh  = (H + 1023) / 1024;

  // ---- workspace layout (ws is ~268 MB; no aliasing needed) ----
  float* wf = (float*)d_ws;
  int*   wi = (int*)d_ws;
  size_t NP = (((size_t)n + 2) + 63) & ~(size_t)63;
  size_t o = 0;
  int*   rp    = wi + o; o += NP;
  int*   bsums = wi + o; o += 384;
  int*   breal = wi + o; o += 512;
  float* dinv  = wf + o; o += NP;
  float* a1v   = wf + o; o += NP;
  float* a1s   = wf + o; o += NP;
  float* a2v   = wf + o; o += NP;
  float* w23   = wf + o; o += 512;
  float* bvA   = wf + o; o += 64;
  float* bvB   = wf + o; o += 64;
  float* slogv = wf + o; o += NP;
  float* elogv = wf + o; o += NP;
  float* pmA   = wf + o; o += 2048;
  float* aval  = wf + o; o += 512;
  int*   aidx  = wi + o; o += 512;
  float* fsc   = wf + o; o += 64;
  int*   isc   = wi + o; o += 64;
  hf*    hh0   = (hf*)(wf + o); o += (size_t)n * 8 + 64;    // n*16 halves
  hf*    hh1   = (hf*)(wf + o); o += (size_t)n * 8 + 64;
  int*   hist  = wi + o; o += (size_t)H + 64;
  int*   csr   = wi + o; o += (size_t)ne + 64;
  int*   pairs = wi + o; o += (size_t)ne + 15 * (size_t)H + 64;  // padded worst case

  const int* row = ei;
  const int* col = ei + ne;

  int gN = (n + TPB - 1) / TPB;

  // ---- CSR build (+ fused edge->float copy in bscatter) ----
  hist_k<<<NBLK, TPB, 0, stream>>>(col, hist, ne, NBKT, NBLK);
  breal_k<<<NBKT, TPB, 0, stream>>>(hist, breal, NBLK);
  scan_single_k<<<1, TPB, 0, stream>>>(breal, NBKT);
  scan1_k<1><<<nbh, TPB, 0, stream>>>(hist, bsums, H);
  scan_single_k<<<1, TPB, 0, stream>>>(bsums, nbh);
  scan3_k<1><<<nbh, TPB, 0, stream>>>(hist, bsums, hist, H, nbh);
  bscatter_k<<<NBLK, TPB, 0, stream>>>(row, col, hist, pairs,
                                       out + OFF5, out + OFF5 + ne + 1, ne, NBKT, NBLK);
  bbuild_k<<<NBKT, TPB, 0, stream>>>(pairs, hist, breal, NBLK, rp, dinv, csr, n, ne);

  // ---- fused-linear GCN: h3 = A^3 (x W1) W23 + a2*bvA + a1*bvB + b3 ----
  prep_k<<<1, TPB, 0, stream>>>(W2, W3, b1, b2, w23, bvA, bvB);
  gemm16h_k<<<(n + 15) / 16, TPB, 0, stream>>>(x, cand, nG, W1, dinv, hh0, n);
  int gH = (n + 31) / 32;
  agghs_k<<<gH, TPB, 0, stream>>>((const h8*)hh0, csr, rp, dinv, dinv, a1v, a1s, (h8*)hh1, n);
  agghs_k<<<gH, TPB, 0, stream>>>((const h8*)hh1, csr, rp, dinv, a1s, a2v, nullptr, (h8*)hh0, n);
  agghc_k<<<gH, TPB, 0, stream>>>((const h8*)hh0, csr, rp, dinv, a1v, a2v,
                                  w23, bvA, bvB, b3, out, n);

  // heads (fused MLPs + softmax partials, LDS-tiled)
  heads_k<<<gN, TPB, 0, stream>>>(out, Ws1, bs1, Ws2, bs2, We1, be1, We2, be2,
                                  slogv, elogv, pmA, n);
  osm_fin_k<<<1, TPB, 0, stream>>>(pmA, fsc, gN);

  // start head: probs + categorical(42)
  pargmax_k<0><<<256, TPB, 0, stream>>>(slogv, fsc, nullptr, out + OFF1, 42u, n, nG, aval, aidx);
  argmax_fin_k<<<1, TPB, 0, stream>>>(aval, aidx, 256, isc, out + OFF3);

  // end head: probs (zero at start) + categorical(43)
  pargmax_k<1><<<256, TPB, 0, stream>>>(elogv, fsc, isc, out + OFF2, 43u, n, nG, aval + 256, aidx + 256);
  argmax_fin_end_k<<<1, TPB, 0, stream>>>(aval + 256, aidx + 256, 256, isc,
                                          out + OFF4, out + OFF5 + ne, out + OFF5 + 2 * (size_t)ne + 1);
}

// Round 13
// 366.528 us; speedup vs baseline: 1.3370x; 1.3370x over previous
//
#include <hip/hip_runtime.h>
#include <math.h>

#define TPB 256
#define BNODES 256     // nodes per bucket (col>>8)
#define EPB 8192       // edges per block in hist/bscatter
#define SENT (-1)
#define MAXBKT 512     // padded bucket-array size (NBKT=395 for this problem)
#define STAGE_CAP 14144  // >= EPB + 15*NBKT(395) = 14117

typedef _Float16 h8 __attribute__((ext_vector_type(8)));
typedef _Float16 hf;

// ===================== threefry2x32-20 (JAX-exact, PARTITIONABLE mode) + gumbel =====================
__device__ __forceinline__ float jax_gumbel(unsigned key, unsigned i) {
  unsigned x0 = 0u, x1 = i;
  unsigned ks0 = 0u, ks1 = key, ks2 = key ^ 0x1BD11BDAu;
  x0 += ks0; x1 += ks1;
#define TFR(r) { x0 += x1; x1 = (x1 << (r)) | (x1 >> (32 - (r))); x1 ^= x0; }
  TFR(13) TFR(15) TFR(26) TFR(6)
  x0 += ks1; x1 += ks2 + 1u;
  TFR(17) TFR(29) TFR(16) TFR(24)
  x0 += ks2; x1 += ks0 + 2u;
  TFR(13) TFR(15) TFR(26) TFR(6)
  x0 += ks0; x1 += ks1 + 3u;
  TFR(17) TFR(29) TFR(16) TFR(24)
  x0 += ks1; x1 += ks2 + 4u;
  TFR(13) TFR(15) TFR(26) TFR(6)
  x0 += ks2; x1 += ks0 + 5u;
#undef TFR
  unsigned bits = x0 ^ x1;
  float f = __uint_as_float((bits >> 9) | 0x3f800000u) - 1.0f;
  float u = (f == 0.0f) ? 1.17549435e-38f : f;
  return -logf(-logf(u));
}

// ===================== pass 1a: coarse bucket histogram (LDS atomics only) =====================
__global__ void hist_k(const int* __restrict__ col, int* __restrict__ hist,
                       int ne, int nbkt, int nblk) {
  __shared__ int h[1024];
  int t = threadIdx.x;
  for (int i = t; i < nbkt; i += TPB) h[i] = 0;
  __syncthreads();
  int base = blockIdx.x * EPB;
#pragma unroll
  for (int k = 0; k < EPB / TPB; k++) {
    int idx = base + k * TPB + t;
    if (idx < ne) atomicAdd(&h[col[idx] >> 8], 1);
  }
  __syncthreads();
  for (int i = t; i < nbkt; i += TPB) hist[(size_t)i * nblk + blockIdx.x] = h[i];
}

// ===================== real per-bucket totals =====================
__global__ void breal_k(const int* __restrict__ hist, int* __restrict__ breal, int nblk) {
  int bkt = blockIdx.x;
  int t = threadIdx.x;
  int s = 0;
  for (int b = t; b < nblk; b += TPB) s += hist[(size_t)bkt * nblk + b];
  __shared__ int red[TPB];
  red[t] = s; __syncthreads();
  for (int st = 128; st > 0; st >>= 1) { if (t < st) red[t] += red[t + st]; __syncthreads(); }
  if (t == 0) breal[bkt] = red[0];
}

// ===================== scans (PAD=1: pad each value to multiple of 16) =====================
template <int PAD>
__global__ void scan1_k(const int* __restrict__ a, int* __restrict__ bsums, int n) {
  int t = threadIdx.x;
  int base = blockIdx.x * 1024 + t * 4;
  int s = 0;
#pragma unroll
  for (int k = 0; k < 4; k++) {
    int i = base + k;
    if (i < n) { int v = a[i]; if (PAD) v = (v + 15) & ~15; s += v; }
  }
  __shared__ int red[TPB];
  red[t] = s; __syncthreads();
  for (int st = 128; st > 0; st >>= 1) { if (t < st) red[t] += red[t + st]; __syncthreads(); }
  if (t == 0) bsums[blockIdx.x] = red[0];
}

__global__ void scan_single_k(int* a, int m) {
  __shared__ int sc[TPB];
  int t = threadIdx.x;
  int v[4]; int s = 0;
#pragma unroll
  for (int k = 0; k < 4; k++) { int i = t * 4 + k; v[k] = (i < m) ? a[i] : 0; s += v[k]; }
  sc[t] = s; __syncthreads();
  for (int off = 1; off < TPB; off <<= 1) {
    int add = (t >= off) ? sc[t - off] : 0;
    __syncthreads();
    sc[t] += add;
    __syncthreads();
  }
  int excl = sc[t] - s;
#pragma unroll
  for (int k = 0; k < 4; k++) { int i = t * 4 + k; if (i < m) a[i] = excl; excl += v[k]; }
  if (t == TPB - 1) a[m] = excl;
}

template <int PAD>
__global__ void scan3_k(const int* __restrict__ a, const int* __restrict__ bsums,
                        int* __restrict__ outp, int n, int nb) {
  int t = threadIdx.x;
  int base = blockIdx.x * 1024 + t * 4;
  int v[4]; int tsum = 0;
#pragma unroll
  for (int k = 0; k < 4; k++) {
    int vv = 0;
    if (base + k < n) { vv = a[base + k]; if (PAD) vv = (vv + 15) & ~15; }
    v[k] = vv; tsum += vv;
  }
  __shared__ int sc[TPB];
  sc[t] = tsum; __syncthreads();
  for (int off = 1; off < TPB; off <<= 1) {
    int add = (t >= off) ? sc[t - off] : 0;
    __syncthreads();
    sc[t] += add;
    __syncthreads();
  }
  int excl = sc[t] - tsum + bsums[blockIdx.x];
#pragma unroll
  for (int k = 0; k < 4; k++) { if (base + k < n) outp[base + k] = excl; excl += v[k]; }
  if (blockIdx.x == 0 && t == 0) outp[n] = bsums[nb];
}

// ===================== pass 1b: LDS-staged bucket scatter + fused edge->float copy ==========
__global__ void __launch_bounds__(TPB, 1)
bscatter_k(const int* __restrict__ row, const int* __restrict__ col,
           const int* __restrict__ histP, int* __restrict__ pairs,
           float* __restrict__ e0, float* __restrict__ e1,
           int ne, int nbkt, int nblk) {
  __shared__ int sbase[MAXBKT], lofs[MAXBKT], lcur[MAXBKT], lsz[MAXBKT];
  __shared__ int ssc[TPB];
  __shared__ int stage[STAGE_CAP];
  int t = threadIdx.x;
  int b = blockIdx.x;
  int i0 = 2 * t, i1 = 2 * t + 1;
  int g0 = 0, L0 = 0, g1 = 0, L1 = 0;
  if (i0 < nbkt) { size_t f = (size_t)i0 * nblk + b; g0 = histP[f]; L0 = histP[f + 1] - g0; }
  if (i1 < nbkt) { size_t f = (size_t)i1 * nblk + b; g1 = histP[f]; L1 = histP[f + 1] - g1; }
  int s = L0 + L1;
  ssc[t] = s; __syncthreads();
  for (int off = 1; off < TPB; off <<= 1) {
    int add = (t >= off) ? ssc[t - off] : 0;
    __syncthreads();
    ssc[t] += add;
    __syncthreads();
  }
  int excl = ssc[t] - s;
  if (i0 < nbkt) { sbase[i0] = g0; lofs[i0] = excl; lcur[i0] = excl; lsz[i0] = L0; }
  if (i1 < nbkt) { sbase[i1] = g1; lofs[i1] = excl + L0; lcur[i1] = excl + L0; lsz[i1] = L1; }
  __syncthreads();
  int base0 = b * EPB;
#pragma unroll
  for (int k = 0; k < EPB / TPB; k++) {
    int idx = base0 + k * TPB + t;
    if (idx < ne) {
      int c = col[idx];
      int r = row[idx];
      int p = atomicAdd(&lcur[c >> 8], 1);
      stage[p] = (r << 8) | (c & 255);
      e0[idx] = (float)r;       // fused edgecopy (coalesced dword stores)
      e1[idx] = (float)c;
    }
  }
  __syncthreads();
  for (int i = t; i < nbkt; i += TPB) {
    int en = lcur[i], pe = lofs[i] + lsz[i];
    for (int p = en; p < pe; p++) stage[p] = SENT;
  }
  __syncthreads();
  int4* gp = (int4*)pairs;
  const int4* sp = (const int4*)stage;
  for (int i = t; i < nbkt; i += TPB) {
    int gb = sbase[i] >> 2, lb = lofs[i] >> 2, m = lsz[i] >> 2;
    for (int q = 0; q < m; q++) gp[gb + q] = sp[lb + q];
  }
}

// ===================== pass 2: per-bucket CSR build =====================
__global__ void bbuild_k(const int* __restrict__ pairs, const int* __restrict__ histP,
                         const int* __restrict__ bbase, int nblk, int* __restrict__ rp,
                         float* __restrict__ dinv, int* __restrict__ csr, int n, int ne) {
  int bkt = blockIdx.x;
  int lo = bkt << 8;
  int t = threadIdx.x;
  int pstart = histP[(size_t)bkt * nblk];
  int pend   = histP[(size_t)(bkt + 1) * nblk];
  int rbase  = bbase[bkt];
  __shared__ int cnt[BNODES], sc[BNODES], pos[BNODES];
  cnt[t] = 0; __syncthreads();
  for (int p = pstart + t; p < pend; p += TPB) {
    int e = pairs[p];
    if (e >= 0) atomicAdd(&cnt[e & 255], 1);
  }
  __syncthreads();
  int own = cnt[t];
  sc[t] = own; __syncthreads();
  for (int off = 1; off < BNODES; off <<= 1) {
    int add = (t >= off) ? sc[t - off] : 0;
    __syncthreads();
    sc[t] += add;
    __syncthreads();
  }
  int excl = sc[t] - own;
  if (lo + t < n) {
    rp[lo + t] = rbase + excl;
    dinv[lo + t] = 1.0f / sqrtf((float)(own + 1));
  }
  pos[t] = rbase + excl;
  __syncthreads();
  for (int p = pstart + t; p < pend; p += TPB) {
    int e = pairs[p];
    if (e >= 0) {
      int q = atomicAdd(&pos[e & 255], 1);
      csr[q] = e >> 8;
    }
  }
  if (bkt == 0 && t == 0) rp[n] = ne;
}

// ===================== prep: W23 = W2@W3 (16x32), bvA = b1@W23, bvB = b2@W3 =====================
__global__ void prep_k(const float* __restrict__ W2, const float* __restrict__ W3,
                       const float* __restrict__ b1, const float* __restrict__ b2,
                       float* __restrict__ W23, float* __restrict__ bvA, float* __restrict__ bvB) {
  int t = threadIdx.x;
  for (int idx = t; idx < 512; idx += TPB) {
    int i = idx >> 5, j = idx & 31;
    float s = 0.f;
    for (int k = 0; k < 24; k++) s += W2[i * 24 + k] * W3[k * 32 + j];
    W23[idx] = s;
  }
  __syncthreads();
  if (t < 32) {
    float sA = 0.f;
    for (int i = 0; i < 16; i++) sA += b1[i] * W23[i * 32 + t];
    bvA[t] = sA;
    float sB = 0.f;
    for (int k = 0; k < 24; k++) sB += b2[k] * W3[k * 32 + t];
    bvB[t] = sB;
  }
}

// ===================== s0 = dinv * (x W1), fp16 output (16-wide) =====================
__global__ void gemm16h_k(const float* __restrict__ A, const float* __restrict__ A2, int nsplit,
                          const float* __restrict__ W, const float* __restrict__ dinv,
                          hf* __restrict__ out, int n) {
  constexpr int FIN = 32, FOUT = 16, FP = 16;
  constexpr int NODES = TPB / FP;
  __shared__ float Ws[FIN * FOUT];
  __shared__ float Hs[NODES * (FIN + 1)];
  int t = threadIdx.x;
  int base = blockIdx.x * NODES;
  for (int i = t; i < FIN * FOUT; i += TPB) Ws[i] = W[i];
  for (int i = t; i < NODES * FIN; i += TPB) {
    int nl = i / FIN, k = i - nl * FIN;
    int g = base + nl;
    float v = 0.f;
    if (g < n) v = (g < nsplit) ? A[(size_t)g * FIN + k] : A2[(size_t)(g - nsplit) * FIN + k];
    Hs[nl * (FIN + 1) + k] = v;
  }
  __syncthreads();
  int nl = t / FP, j = t % FP;
  int g = base + nl;
  if (g < n) {
    float acc = 0.f;
#pragma unroll
    for (int k = 0; k < FIN; k++) acc += Hs[nl * (FIN + 1) + k] * Ws[k * FOUT + j];
    out[(size_t)g * FOUT + j] = (hf)(acc * dinv[g]);
  }
}

// ===================== fp16 hop + fused scalar chain: 8 nodes/wave =====================
__global__ void agghs_k(const h8* __restrict__ ts, const int* __restrict__ csr,
                        const int* __restrict__ rp, const float* __restrict__ dinv,
                        const float* __restrict__ sin, float* __restrict__ u_out,
                        float* __restrict__ us_out, h8* __restrict__ outv, int n) {
  int wave = blockIdx.x * (TPB / 64) + (threadIdx.x >> 6);
  int lane = threadIdx.x & 63;
  int j = lane & 1;
  int grp = (lane >> 1) & 3;
  int nl = lane >> 3;
  int c = wave * 8 + nl;
  bool valid = (c < n);
  float acc[8] = {0.f, 0.f, 0.f, 0.f, 0.f, 0.f, 0.f, 0.f};
  float accS = 0.f;
  if (valid) {
    int s = rp[c], e = rp[c + 1];
    for (int p = s + grp; p < e; p += 4) {
      int r = csr[p];
      h8 v = ts[r * 2 + j];
#pragma unroll
      for (int k = 0; k < 8; k++) acc[k] += (float)v[k];
      if (j == 0) accS += sin[r];
    }
  }
#pragma unroll
  for (int off = 2; off <= 4; off <<= 1) {
#pragma unroll
    for (int k = 0; k < 8; k++) acc[k] += __shfl_xor(acc[k], off, 64);
    accS += __shfl_xor(accS, off, 64);
  }
  if (valid && grp == 0) {
    h8 self = ts[c * 2 + j];
    float d = dinv[c];
    float scl = d * d;
    h8 o;
#pragma unroll
    for (int k = 0; k < 8; k++) o[k] = (hf)(scl * (acc[k] + (float)self[k]));
    outv[c * 2 + j] = o;
    if (j == 0) {
      float u = d * (accS + sin[c]);
      u_out[c] = u;
      if (us_out) us_out[c] = u * d;
    }
  }
}

// ===================== final hop + fused combine (8 nodes/wave, 32 nodes/block) =====================
__global__ void agghc_k(const h8* __restrict__ ts, const int* __restrict__ csr,
                        const int* __restrict__ rp, const float* __restrict__ dinv,
                        const float* __restrict__ a1, const float* __restrict__ a2,
                        const float* __restrict__ W23, const float* __restrict__ bvA,
                        const float* __restrict__ bvB, const float* __restrict__ b3,
                        float* __restrict__ out, int n) {
  __shared__ float Ws[512], vA[32], vB[32], vb[32];
  __shared__ float t3s[32][17];
  int t = threadIdx.x;
  for (int i = t; i < 512; i += TPB) Ws[i] = W23[i];
  if (t < 32) { vA[t] = bvA[t]; vB[t] = bvB[t]; vb[t] = b3[t]; }
  int wave = t >> 6;
  int lane = t & 63;
  int j = lane & 1;
  int grp = (lane >> 1) & 3;
  int nl = lane >> 3;
  int nlb = wave * 8 + nl;              // node-in-block 0..31
  int c = blockIdx.x * 32 + nlb;
  bool valid = (c < n);
  float acc[8] = {0.f, 0.f, 0.f, 0.f, 0.f, 0.f, 0.f, 0.f};
  if (valid) {
    int s = rp[c], e = rp[c + 1];
    for (int p = s + grp; p < e; p += 4) {
      int r = csr[p];
      h8 v = ts[r * 2 + j];
#pragma unroll
      for (int k = 0; k < 8; k++) acc[k] += (float)v[k];
    }
  }
#pragma unroll
  for (int off = 2; off <= 4; off <<= 1) {
#pragma unroll
    for (int k = 0; k < 8; k++) acc[k] += __shfl_xor(acc[k], off, 64);
  }
  if (valid && grp == 0) {
    h8 self = ts[c * 2 + j];
    float d = dinv[c];
#pragma unroll
    for (int k = 0; k < 8; k++) t3s[nlb][j * 8 + k] = d * (acc[k] + (float)self[k]);
  }
  __syncthreads();
  int n2 = t >> 3, jb = t & 7;          // 32 nodes x 8 base channels
  int g = blockIdx.x * 32 + n2;
  if (g < n) {
    float av = a1[g], bv = a2[g];
#pragma unroll
    for (int q = 0; q < 4; q++) {
      int j2 = jb + q * 8;
      float acc2 = 0.f;
#pragma unroll
      for (int k = 0; k < 16; k++) acc2 += t3s[n2][k] * Ws[k * 32 + j2];
      out[(size_t)g * 32 + j2] = acc2 + bv * vA[j2] + av * vB[j2] + vb[j2];
    }
  }
}

// ===================== fused heads + online-softmax partials =====================
// __launch_bounds__(TPB, 2): 2 blocks/CU min -> up to ~256 VGPR/thread, NO scratch spill
// (default 8-wave target capped at 64 VGPR and spilled row[32] -> 270 MB scratch traffic, R11/R12).
// pm layout (stride 512): [0..)=m1, [512..)=s1, [1024..)=m2, [1536..)=s2
__global__ void __launch_bounds__(TPB, 2)
heads_k(const float* __restrict__ h3,
        const float* __restrict__ Ws1, const float* __restrict__ bs1,
        const float* __restrict__ ws2, const float* __restrict__ bs2,
        const float* __restrict__ We1, const float* __restrict__ be1,
        const float* __restrict__ we2, const float* __restrict__ be2,
        float* __restrict__ slog, float* __restrict__ elog,
        float* __restrict__ pm, int n) {
  __shared__ float W1s[32 * 16], W2s[32 * 24], b1s[16], b2s[24], v1s[16], v2s[24];
  int t = threadIdx.x;
  for (int i = t; i < 32 * 16; i += TPB) W1s[i] = Ws1[i];
  for (int i = t; i < 32 * 24; i += TPB) W2s[i] = We1[i];
  if (t < 16) { b1s[t] = bs1[t]; v1s[t] = ws2[t]; }
  if (t < 24) { b2s[t] = be1[t]; v2s[t] = we2[t]; }
  __syncthreads();
  int i = blockIdx.x * TPB + t;
  float s = -3.402823466e+38f, e2 = -3.402823466e+38f;
  if (i < n) {
    float row[32];
#pragma unroll
    for (int k = 0; k < 32; k++) row[k] = h3[(size_t)i * 32 + k];
    s = bs2[0];
#pragma unroll
    for (int j = 0; j < 16; j++) {
      float a = b1s[j];
#pragma unroll
      for (int k = 0; k < 32; k++) a += row[k] * W1s[k * 16 + j];
      a = fminf(fmaxf(a, 0.f), 6.f);
      s += a * v1s[j];
    }
    e2 = be2[0];
#pragma unroll
    for (int j = 0; j < 24; j++) {
      float a = b2s[j];
#pragma unroll
      for (int k = 0; k < 32; k++) a += row[k] * W2s[k * 24 + j];
      a = fminf(fmaxf(a, 0.f), 6.f);
      e2 += a * v2s[j];
    }
    slog[i] = s;
    elog[i] = e2;
  }
  // block online-softmax partials (invalid lanes carry m=-FLT_MAX, s=0)
  __shared__ float sm1[TPB], ss1[TPB], sm2[TPB], ss2[TPB];
  sm1[t] = s;  ss1[t] = (i < n) ? 1.f : 0.f;
  sm2[t] = e2; ss2[t] = (i < n) ? 1.f : 0.f;
  __syncthreads();
  for (int st = 128; st > 0; st >>= 1) {
    if (t < st) {
      float M = fmaxf(sm1[t], sm1[t + st]);
      ss1[t] = ss1[t] * expf(sm1[t] - M) + ss1[t + st] * expf(sm1[t + st] - M);
      sm1[t] = M;
      float M2 = fmaxf(sm2[t], sm2[t + st]);
      ss2[t] = ss2[t] * expf(sm2[t] - M2) + ss2[t + st] * expf(sm2[t + st] - M2);
      sm2[t] = M2;
    }
    __syncthreads();
  }
  if (t == 0) {
    pm[blockIdx.x] = sm1[0]; pm[512 + blockIdx.x] = ss1[0];
    pm[1024 + blockIdx.x] = sm2[0]; pm[1536 + blockIdx.x] = ss2[0];
  }
}

__global__ void osm_fin_k(const float* __restrict__ pm, float* __restrict__ fsc, int nb) {
  int t = threadIdx.x;
  float m1 = -3.402823466e+38f, s1 = 0.f, m2 = -3.402823466e+38f, s2 = 0.f;
  for (int i = t; i < nb; i += TPB) {
    float bm1 = pm[i], bs1v = pm[512 + i];
    float M = fmaxf(m1, bm1);
    s1 = s1 * expf(m1 - M) + bs1v * expf(bm1 - M); m1 = M;
    float bm2 = pm[1024 + i], bs2v = pm[1536 + i];
    float M2 = fmaxf(m2, bm2);
    s2 = s2 * expf(m2 - M2) + bs2v * expf(bm2 - M2); m2 = M2;
  }
  __shared__ float sm1[TPB], ss1[TPB], sm2[TPB], ss2[TPB];
  sm1[t] = m1; ss1[t] = s1; sm2[t] = m2; ss2[t] = s2; __syncthreads();
  for (int st = 128; st > 0; st >>= 1) {
    if (t < st) {
      float M = fmaxf(sm1[t], sm1[t + st]);
      ss1[t] = ss1[t] * expf(sm1[t] - M) + ss1[t + st] * expf(sm1[t + st] - M);
      sm1[t] = M;
      float M2 = fmaxf(sm2[t], sm2[t + st]);
      ss2[t] = ss2[t] * expf(sm2[t] - M2) + ss2[t + st] * expf(sm2[t + st] - M2);
      sm2[t] = M2;
    }
    __syncthreads();
  }
  if (t == 0) { fsc[0] = sm1[0]; fsc[2] = ss1[0]; fsc[1] = sm2[0]; fsc[3] = ss2[0]; }
}

// ===================== fused probs write + gumbel argmax =====================
template <int HEAD>
__global__ void pargmax_k(const float* __restrict__ logit, const float* __restrict__ fsc,
                          const int* __restrict__ isc, float* __restrict__ outp,
                          unsigned key, int n, int ngraph, float* pval, int* pidx) {
  int t = threadIdx.x;
  float mx = fsc[HEAD], sm = fsc[2 + HEAD];
  int ban = HEAD ? isc[0] : -1;
  float bv = -3.402823466e+38f;
  int bi = 0x7fffffff;
  for (int i = blockIdx.x * TPB + t; i < n; i += gridDim.x * TPB) {
    float p = expf(logit[i] - mx) / sm;
    if (HEAD == 0) { if (i >= ngraph) p = 0.f; }
    else           { if (i == ban) p = 0.f; }
    if (p == 0.f) p = 1e-10f;
    outp[i] = p;
    float v = logf(p) + jax_gumbel(key, (unsigned)i);
    if (v > bv) { bv = v; bi = i; }
  }
  __shared__ float sv[TPB]; __shared__ int si[TPB];
  sv[t] = bv; si[t] = bi; __syncthreads();
  for (int st = 128; st > 0; st >>= 1) {
    if (t < st) {
      float v2 = sv[t + st]; int i2 = si[t + st];
      if (v2 > sv[t] || (v2 == sv[t] && i2 < si[t])) { sv[t] = v2; si[t] = i2; }
    }
    __syncthreads();
  }
  if (t == 0) { pval[blockIdx.x] = sv[0]; pidx[blockIdx.x] = si[0]; }
}

__global__ void argmax_fin_k(const float* pval, const int* pidx, int nb,
                             int* isc, float* dnode) {
  int t = threadIdx.x;
  float bv = (t < nb) ? pval[t] : -3.402823466e+38f;
  int bi = (t < nb) ? pidx[t] : 0x7fffffff;
  __shared__ float sv[TPB]; __shared__ int si[TPB];
  sv[t] = bv; si[t] = bi; __syncthreads();
  for (int st = 128; st > 0; st >>= 1) {
    if (t < st) {
      float v2 = sv[t + st]; int i2 = si[t + st];
      if (v2 > sv[t] || (v2 == sv[t] && i2 < si[t])) { sv[t] = v2; si[t] = i2; }
    }
    __syncthreads();
  }
  if (t == 0) { isc[0] = si[0]; dnode[0] = (float)si[0]; }
}

__global__ void argmax_fin_end_k(const float* pval, const int* pidx, int nb,
                                 const int* isc, float* p_end, float* p_e0, float* p_e1) {
  int t = threadIdx.x;
  float bv = (t < nb) ? pval[t] : -3.402823466e+38f;
  int bi = (t < nb) ? pidx[t] : 0x7fffffff;
  __shared__ float sv[TPB]; __shared__ int si[TPB];
  sv[t] = bv; si[t] = bi; __syncthreads();
  for (int st = 128; st > 0; st >>= 1) {
    if (t < st) {
      float v2 = sv[t + st]; int i2 = si[t + st];
      if (v2 > sv[t] || (v2 == sv[t] && i2 < si[t])) { sv[t] = v2; si[t] = i2; }
    }
    __syncthreads();
  }
  if (t == 0) {
    int en = si[0];
    p_end[0] = (float)en;
    p_e0[0] = (float)isc[0];
    p_e1[0] = (float)en;
  }
}

// ===================== launch =====================
extern "C" void kernel_launch(void* const* d_in, const int* in_sizes, int n_in,
                              void* d_out, int out_size, void* d_ws, size_t ws_size,
                              hipStream_t stream) {
  const float* x    = (const float*)d_in[0];
  const float* cand = (const float*)d_in[1];
  const int*   ei   = (const int*)d_in[2];
  const float* W1 = (const float*)d_in[3];  const float* b1  = (const float*)d_in[4];
  const float* W2 = (const float*)d_in[5];  const float* b2  = (const float*)d_in[6];
  const float* W3 = (const float*)d_in[7];  const float* b3  = (const float*)d_in[8];
  const float* Ws1= (const float*)d_in[9];  const float* bs1 = (const float*)d_in[10];
  const float* Ws2= (const float*)d_in[11]; const float* bs2 = (const float*)d_in[12];
  const float* We1= (const float*)d_in[13]; const float* be1 = (const float*)d_in[14];
  const float* We2= (const float*)d_in[15]; const float* be2 = (const float*)d_in[16];

  const int nG = in_sizes[0] / 32, nC = in_sizes[1] / 32;
  const int n  = nG + nC;            // 101000
  const int ne = in_sizes[2] / 2;    // 3200000

  float* out = (float*)d_out;
  const size_t OFF1 = (size_t)n * 32;
  const size_t OFF2 = OFF1 + n;
  const size_t OFF3 = OFF2 + n;
  const size_t OFF4 = OFF3 + 1;
  const size_t OFF5 = OFF4 + 1;     // edge_index_new region: 2*(ne+1) floats

  const int NBKT = (n + BNODES - 1) / BNODES;
  const int NBLK = (ne + EPB - 1) / EPB;
  const int H    = NBKT * NBLK;
  const int nbh  = (H + 1023) / 1024;

  // ---- workspace layout (ws is ~268 MB; no aliasing needed) ----
  float* wf = (float*)d_ws;
  int*   wi = (int*)d_ws;
  size_t NP = (((size_t)n + 2) + 63) & ~(size_t)63;
  size_t o = 0;
  int*   rp    = wi + o; o += NP;
  int*   bsums = wi + o; o += 384;
  int*   breal = wi + o; o += 512;
  float* dinv  = wf + o; o += NP;
  float* a1v   = wf + o; o += NP;
  float* a1s   = wf + o; o += NP;
  float* a2v   = wf + o; o += NP;
  float* w23   = wf + o; o += 512;
  float* bvA   = wf + o; o += 64;
  float* bvB   = wf + o; o += 64;
  float* slogv = wf + o; o += NP;
  float* elogv = wf + o; o += NP;
  float* pmA   = wf + o; o += 2048;
  float* aval  = wf + o; o += 512;
  int*   aidx  = wi + o; o += 512;
  float* fsc   = wf + o; o += 64;
  int*   isc   = wi + o; o += 64;
  hf*    hh0   = (hf*)(wf + o); o += (size_t)n * 8 + 64;    // n*16 halves
  hf*    hh1   = (hf*)(wf + o); o += (size_t)n * 8 + 64;
  int*   hist  = wi + o; o += (size_t)H + 64;
  int*   csr   = wi + o; o += (size_t)ne + 64;
  int*   pairs = wi + o; o += (size_t)ne + 15 * (size_t)H + 64;  // padded worst case

  const int* row = ei;
  const int* col = ei + ne;

  int gN = (n + TPB - 1) / TPB;

  // ---- CSR build (+ fused edge->float copy in bscatter) ----
  hist_k<<<NBLK, TPB, 0, stream>>>(col, hist, ne, NBKT, NBLK);
  breal_k<<<NBKT, TPB, 0, stream>>>(hist, breal, NBLK);
  scan_single_k<<<1, TPB, 0, stream>>>(breal, NBKT);
  scan1_k<1><<<nbh, TPB, 0, stream>>>(hist, bsums, H);
  scan_single_k<<<1, TPB, 0, stream>>>(bsums, nbh);
  scan3_k<1><<<nbh, TPB, 0, stream>>>(hist, bsums, hist, H, nbh);
  bscatter_k<<<NBLK, TPB, 0, stream>>>(row, col, hist, pairs,
                                       out + OFF5, out + OFF5 + ne + 1, ne, NBKT, NBLK);
  bbuild_k<<<NBKT, TPB, 0, stream>>>(pairs, hist, breal, NBLK, rp, dinv, csr, n, ne);

  // ---- fused-linear GCN: h3 = A^3 (x W1) W23 + a2*bvA + a1*bvB + b3 ----
  prep_k<<<1, TPB, 0, stream>>>(W2, W3, b1, b2, w23, bvA, bvB);
  gemm16h_k<<<(n + 15) / 16, TPB, 0, stream>>>(x, cand, nG, W1, dinv, hh0, n);
  int gH = (n + 31) / 32;
  agghs_k<<<gH, TPB, 0, stream>>>((const h8*)hh0, csr, rp, dinv, dinv, a1v, a1s, (h8*)hh1, n);
  agghs_k<<<gH, TPB, 0, stream>>>((const h8*)hh1, csr, rp, dinv, a1s, a2v, nullptr, (h8*)hh0, n);
  agghc_k<<<gH, TPB, 0, stream>>>((const h8*)hh0, csr, rp, dinv, a1v, a2v,
                                  w23, bvA, bvB, b3, out, n);

  // heads (fused MLPs + softmax partials, launch_bounds fixes spill)
  heads_k<<<gN, TPB, 0, stream>>>(out, Ws1, bs1, Ws2, bs2, We1, be1, We2, be2,
                                  slogv, elogv, pmA, n);
  osm_fin_k<<<1, TPB, 0, stream>>>(pmA, fsc, gN);

  // start head: probs + categorical(42)
  pargmax_k<0><<<256, TPB, 0, stream>>>(slogv, fsc, nullptr, out + OFF1, 42u, n, nG, aval, aidx);
  argmax_fin_k<<<1, TPB, 0, stream>>>(aval, aidx, 256, isc, out + OFF3);

  // end head: probs (zero at start) + categorical(43)
  pargmax_k<1><<<256, TPB, 0, stream>>>(elogv, fsc, isc, out + OFF2, 43u, n, nG, aval + 256, aidx + 256);
  argmax_fin_end_k<<<1, TPB, 0, stream>>>(aval + 256, aidx + 256, 256, isc,
                                          out + OFF4, out + OFF5 + ne, out + OFF5 + 2 * (size_t)ne + 1);
}